// Round 7
// baseline (703.948 us; speedup 1.0000x reference)
//
#include <hip/hip_runtime.h>
#include <math.h>

#define PI_F 3.14159265358979323846f
// swizzles: XOR bank-index bits with higher address bits (bijective, both sides)
#define SWZ16(i) ((i) ^ (((i) >> 4) & 15))  // 4-bit XOR: full odd/even bank spread
#define SWZ8(i)  ((i) ^ (((i) >> 3) & 7))   // used for Wd tile in down-proj phase

// ---------------- Kernel 0: build circular-conv tables from complex spectral weights --
__global__ __launch_bounds__(256) void build_tables(
    const float* __restrict__ cw_x, const float* __restrict__ cw_z,
    float* __restrict__ KKx, float* __restrict__ KKz)
{
    int tid = blockIdx.x * 256 + threadIdx.x;
    if (tid < 2048) {                    // X branch: S=16, V=9
        int c = tid & 7;
        int ab = tid >> 3;               // a*16+b
        int a = ab >> 4, b = ab & 15;
        float acc = 0.f;
        for (int u = 0; u < 16; ++u) {
            for (int v = 0; v < 9; ++v) {
                float m = (v == 0 || v == 8) ? 1.f : 2.f;
                int ph = (u * a + v * b) & 15;
                float th = (2.f * PI_F / 16.f) * (float)ph;
                float sn, cs;
                sincosf(th, &sn, &cs);
                const float* wp = cw_x + (size_t)((u * 9 + v) * 8 + c) * 2;
                acc += m * (wp[0] * cs - wp[1] * sn);
            }
        }
        KKx[ab * 8 + c] = acc * (1.f / 256.f);
    } else if (tid < 2048 + 512) {       // Z branch: S=8, V=5
        int e = tid - 2048;
        int c = e & 7;
        int ab = e >> 3;                 // a*8+b
        int a = ab >> 3, b = ab & 7;
        float acc = 0.f;
        for (int u = 0; u < 8; ++u) {
            for (int v = 0; v < 5; ++v) {
                float m = (v == 0 || v == 4) ? 1.f : 2.f;
                int ph = (u * a + v * b) & 7;
                float th = (2.f * PI_F / 8.f) * (float)ph;
                float sn, cs;
                sincosf(th, &sn, &cs);
                const float* wp = cw_z + (size_t)((u * 5 + v) * 8 + c) * 2;
                acc += m * (wp[0] * cs - wp[1] * sn);
            }
        }
        KKz[ab * 8 + c] = acc * (1.f / 64.f);
    }
}

// ======================= shared phase bodies (512-thread blocks) =====================
// job space is fixed at 512 jobs per phase; kernels pass gridDim.x as nblk.

// ---- phase 1: h = x @ Wd + bd. Job = 160 rows (32 groups x 16 lanes x 5 rows). ----
__device__ __forceinline__ void phase1_all(int t, int bid, int nblk,
    const float* __restrict__ x, const float* __restrict__ Wd,
    const float* __restrict__ bd, float* __restrict__ hg)
{
    __shared__ float4 wds[1536];         // 24KB, swizzled
    const float4* Wd4 = (const float4*)Wd;
    for (int i = t; i < 1536; i += 512) wds[SWZ8(i)] = Wd4[i];
    __syncthreads();

    for (int job = bid; job < 512; job += nblk) {
        int G = job * 32 + (t >> 4);     // group id, 16384 total
        int l = t & 15;
        const float4* xr = (const float4*)x + (size_t)G * 5 * 192;
        float acc[5][8];
        #pragma unroll
        for (int r = 0; r < 5; ++r)
            #pragma unroll
            for (int c = 0; c < 8; ++c) acc[r][c] = 0.f;
        #pragma unroll
        for (int j = 0; j < 12; ++j) {
            float4 v[5];
            #pragma unroll
            for (int r = 0; r < 5; ++r) v[r] = xr[(size_t)r * 192 + l + 16 * j];
            #pragma unroll
            for (int e = 0; e < 4; ++e) {
                int f4i = ((l + 16 * j) * 4 + e) * 2;        // even
                int sw = SWZ8(f4i);
                float4 w0 = wds[sw];
                float4 w1 = wds[sw ^ 1];                     // SWZ8(f4i+1)==SWZ8(f4i)^1
                #pragma unroll
                for (int r = 0; r < 5; ++r) {
                    float xv = (e == 0) ? v[r].x : (e == 1) ? v[r].y : (e == 2) ? v[r].z : v[r].w;
                    acc[r][0] += xv * w0.x;  acc[r][1] += xv * w0.y;
                    acc[r][2] += xv * w0.z;  acc[r][3] += xv * w0.w;
                    acc[r][4] += xv * w1.x;  acc[r][5] += xv * w1.y;
                    acc[r][6] += xv * w1.z;  acc[r][7] += xv * w1.w;
                }
            }
        }
        #pragma unroll
        for (int off = 1; off < 16; off <<= 1)
            #pragma unroll
            for (int r = 0; r < 5; ++r)
                #pragma unroll
                for (int c = 0; c < 8; ++c)
                    acc[r][c] += __shfl_xor(acc[r][c], off, 64);
        if (l < 5) {
            float o[8];
            #pragma unroll
            for (int c = 0; c < 8; ++c)
                o[c] = (l == 0) ? acc[0][c] : (l == 1) ? acc[1][c] :
                       (l == 2) ? acc[2][c] : (l == 3) ? acc[3][c] : acc[4][c];
            float4* hp = (float4*)hg + ((size_t)G * 5 + l) * 2;
            hp[0] = make_float4(o[0] + bd[0], o[1] + bd[1], o[2] + bd[2], o[3] + bd[3]);
            hp[1] = make_float4(o[4] + bd[4], o[5] + bd[5], o[6] + bd[6], o[7] + bd[7]);
        }
    }
}

// ---- phase 2: LN1 -> circular conv -> LN2 -> MLP -> catg. Job = half batch. ----
__device__ __forceinline__ void phase2_all(int t, int bid, int nblk,
    const float* __restrict__ hg,
    const float* __restrict__ KKx, const float* __restrict__ KKz,
    const float* __restrict__ g1v, const float* __restrict__ b1v,
    const float* __restrict__ g2v, const float* __restrict__ b2v,
    const float* __restrict__ W1, const float* __restrict__ b1m,
    const float* __restrict__ W2, const float* __restrict__ b2m,
    float* __restrict__ catg)
{
    __shared__ float4 kkx[512];       // 8KB
    __shared__ float4 kkz[128];       // 2KB
    __shared__ float4 t1x[512];       // 8KB (swizzled)
    __shared__ float4 t1z[128];       // 2KB (swizzled)

    kkx[t & 511] = ((const float4*)KKx)[t & 511];
    if (t < 128) kkz[t] = ((const float4*)KKz)[t];

    for (int job = bid; job < 512; job += nblk) {
        int batch = job >> 1, half = job & 1;
        __syncthreads();                 // staging visible / t1 safe to overwrite
        if (t < 320) {                   // rebuild full t1 tile (tok = t)
            const float4* hp = (const float4*)hg + ((size_t)batch * 320 + t) * 2;
            float4 r0 = hp[0], r1 = hp[1];
            float raw[8] = {r0.x, r0.y, r0.z, r0.w, r1.x, r1.y, r1.z, r1.w};
            float mean = 0.f;
            #pragma unroll
            for (int c = 0; c < 8; ++c) mean += raw[c];
            mean *= 0.125f;
            float var = 0.f;
            #pragma unroll
            for (int c = 0; c < 8; ++c) { float d = raw[c] - mean; var += d * d; }
            var *= 0.125f;
            float inv = rsqrtf(var + 1e-5f);
            float t1[8];
            #pragma unroll
            for (int c = 0; c < 8; ++c) t1[c] = (raw[c] - mean) * inv * g1v[c] + b1v[c];
            if (t >= 64) {               // X token t-64
                int i0 = 2 * (t - 64);
                t1x[SWZ16(i0)]     = make_float4(t1[0], t1[1], t1[2], t1[3]);
                t1x[SWZ16(i0 + 1)] = make_float4(t1[4], t1[5], t1[6], t1[7]);
            } else {                     // Z token t
                int i0 = 2 * t;
                t1z[SWZ16(i0)]     = make_float4(t1[0], t1[1], t1[2], t1[3]);
                t1z[SWZ16(i0 + 1)] = make_float4(t1[4], t1[5], t1[6], t1[7]);
            }
        }
        __syncthreads();

        if (t < 160) {
            bool isX = (t < 128);
            int tok;
            float s0=0.f,s1=0.f,s2=0.f,s3=0.f,s4=0.f,s5=0.f,s6=0.f,s7=0.f;
            if (isX) {
                int xo = half * 128 + t;     // X output token 0..255
                tok = 64 + xo;
                int p = xo >> 4, q = xo & 15;
                for (int da = 0; da < 16; ++da) {
                    int qp = (q - da) & 15;
                    #pragma unroll
                    for (int db = 0; db < 16; ++db) {
                        int pp = (p - db) & 15;
                        int si = (pp * 16 + qp) * 2;            // even
                        int sw = SWZ16(si);
                        float4 v0 = t1x[sw];
                        float4 v1 = t1x[sw ^ 1];                // SWZ16(si+1)==SWZ16(si)^1
                        int kb = (da * 16 + db) * 2;
                        float4 k0 = kkx[kb], k1 = kkx[kb + 1];  // uniform -> broadcast
                        s0 += k0.x * v0.x;  s1 += k0.y * v0.y;
                        s2 += k0.z * v0.z;  s3 += k0.w * v0.w;
                        s4 += k1.x * v1.x;  s5 += k1.y * v1.y;
                        s6 += k1.z * v1.z;  s7 += k1.w * v1.w;
                    }
                }
            } else {
                int zo = half * 32 + (t - 128);  // Z output token 0..63
                tok = zo;
                int p = zo >> 3, q = zo & 7;
                for (int da = 0; da < 8; ++da) {
                    int qp = (q - da) & 7;
                    #pragma unroll
                    for (int db = 0; db < 8; ++db) {
                        int pp = (p - db) & 7;
                        int si = (pp * 8 + qp) * 2;             // even
                        int sw = SWZ16(si);
                        float4 v0 = t1z[sw];
                        float4 v1 = t1z[sw ^ 1];
                        int kb = (da * 8 + db) * 2;
                        float4 k0 = kkz[kb], k1 = kkz[kb + 1];
                        s0 += k0.x * v0.x;  s1 += k0.y * v0.y;
                        s2 += k0.z * v0.z;  s3 += k0.w * v0.w;
                        s4 += k1.x * v1.x;  s5 += k1.y * v1.y;
                        s6 += k1.z * v1.z;  s7 += k1.w * v1.w;
                    }
                }
            }

            const float4* hp = (const float4*)hg + ((size_t)batch * 320 + tok) * 2;
            float4 r0 = hp[0], r1 = hp[1];
            float raw[8] = {r0.x, r0.y, r0.z, r0.w, r1.x, r1.y, r1.z, r1.w};

            float sarr[8] = {s0, s1, s2, s3, s4, s5, s6, s7};
            float m2 = 0.f;
            #pragma unroll
            for (int c = 0; c < 8; ++c) m2 += sarr[c];
            m2 *= 0.125f;
            float v2 = 0.f;
            #pragma unroll
            for (int c = 0; c < 8; ++c) { float d = sarr[c] - m2; v2 += d * d; }
            v2 *= 0.125f;
            float inv2 = rsqrtf(v2 + 1e-5f);
            float t2[8];
            #pragma unroll
            for (int c = 0; c < 8; ++c) t2[c] = (sarr[c] - m2) * inv2 * g2v[c] + b2v[c];

            float hm[16];
            #pragma unroll
            for (int j = 0; j < 16; ++j) {
                float acc = b1m[j];
                #pragma unroll
                for (int c = 0; c < 8; ++c) acc += t2[c] * W1[c * 16 + j];
                hm[j] = 0.5f * acc * (1.f + erff(acc * 0.70710678118654752f));  // exact GELU
            }
            float o[8];
            #pragma unroll
            for (int c = 0; c < 8; ++c) {
                float acc = b2m[c];
                #pragma unroll
                for (int j = 0; j < 16; ++j) acc += hm[j] * W2[j * 8 + c];
                o[c] = acc + raw[c];
            }
            float4* cp = (float4*)catg + ((size_t)batch * 320 + tok) * 2;
            cp[0] = make_float4(o[0], o[1], o[2], o[3]);
            cp[1] = make_float4(o[4], o[5], o[6], o[7]);
        }
    }
}

// ---- phase 3: out = cat @ Wu + bu. Job = 160 rows (8 waves x 20 rows). ----
__device__ __forceinline__ void phase3_all(int t, int bid, int nblk,
    const float* __restrict__ catg, const float* __restrict__ Wu,
    const float* __restrict__ bu, float* __restrict__ out)
{
    int wv = t >> 6;                 // 0..7
    int ln = t & 63;
    const float4* Wu4 = (const float4*)Wu;
    float4 wr[24];                   // [c*3+k] = 96 VGPRs (fits 128 cap; R5-proven)
    #pragma unroll
    for (int c = 0; c < 8; ++c)
        #pragma unroll
        for (int k = 0; k < 3; ++k)
            wr[c * 3 + k] = Wu4[c * 192 + ln + 64 * k];
    float4 bv[3];
    #pragma unroll
    for (int k = 0; k < 3; ++k) bv[k] = ((const float4*)bu)[ln + 64 * k];

    for (int job = bid; job < 512; job += nblk) {
        int row0 = (job * 8 + wv) * 20;
        #pragma unroll 4
        for (int r = 0; r < 20; ++r) {
            int row = row0 + r;
            float cv[8];
            #pragma unroll
            for (int c = 0; c < 8; ++c) cv[c] = catg[(size_t)row * 8 + c];  // uniform
            float4* o4 = (float4*)out + (size_t)row * 192 + ln;
            #pragma unroll
            for (int k = 0; k < 3; ++k) {
                float4 a = bv[k];
                #pragma unroll
                for (int c = 0; c < 8; ++c) {
                    a.x += cv[c] * wr[c * 3 + k].x;
                    a.y += cv[c] * wr[c * 3 + k].y;
                    a.z += cv[c] * wr[c * 3 + k].z;
                    a.w += cv[c] * wr[c * 3 + k].w;
                }
                o4[64 * k] = a;          // 64 lanes x 16B = 1KB contiguous
            }
        }
    }
}

// ======================= thin kernels (split path) ===================================
// __launch_bounds__(512,4): 4 waves/EU -> 2 blocks/CU (16 waves/CU), VGPR cap 128.
__global__ __launch_bounds__(512, 4) void k_p1(
    const float* __restrict__ x, const float* __restrict__ Wd,
    const float* __restrict__ bd, float* __restrict__ hg)
{
    phase1_all(threadIdx.x, blockIdx.x, gridDim.x, x, Wd, bd, hg);
}

__global__ __launch_bounds__(512, 4) void k_p2(
    const float* __restrict__ hg,
    const float* __restrict__ KKx, const float* __restrict__ KKz,
    const float* __restrict__ g1v, const float* __restrict__ b1v,
    const float* __restrict__ g2v, const float* __restrict__ b2v,
    const float* __restrict__ W1, const float* __restrict__ b1m,
    const float* __restrict__ W2, const float* __restrict__ b2m,
    float* __restrict__ catg)
{
    phase2_all(threadIdx.x, blockIdx.x, gridDim.x, hg, KKx, KKz,
               g1v, b1v, g2v, b2v, W1, b1m, W2, b2m, catg);
}

__global__ __launch_bounds__(512, 4) void k_p3(
    const float* __restrict__ catg, const float* __restrict__ Wu,
    const float* __restrict__ bu, float* __restrict__ out)
{
    phase3_all(threadIdx.x, blockIdx.x, gridDim.x, catg, Wu, bu, out);
}

extern "C" void kernel_launch(void* const* d_in, const int* in_sizes, int n_in,
                              void* d_out, int out_size, void* d_ws, size_t ws_size,
                              hipStream_t stream)
{
    (void)in_sizes; (void)n_in; (void)out_size; (void)ws_size;
    const float* x    = (const float*)d_in[0];
    const float* Wd   = (const float*)d_in[1];
    const float* bd   = (const float*)d_in[2];
    const float* cw_x = (const float*)d_in[3];
    const float* cw_z = (const float*)d_in[4];
    const float* g1   = (const float*)d_in[5];
    const float* h1   = (const float*)d_in[6];
    const float* g2   = (const float*)d_in[7];
    const float* h2   = (const float*)d_in[8];
    const float* W1   = (const float*)d_in[9];
    const float* b1   = (const float*)d_in[10];
    const float* W2   = (const float*)d_in[11];
    const float* b2   = (const float*)d_in[12];
    const float* Wu   = (const float*)d_in[13];
    const float* bu   = (const float*)d_in[14];
    float* out = (float*)d_out;

    float* KKx = (float*)d_ws;          // 2048 floats
    float* KKz = KKx + 2048;            // 512 floats
    float* hg  = KKz + 512;             // 655360 floats
    float* ctg = hg + 655360;           // 655360 floats

    hipLaunchKernelGGL(build_tables, dim3(10), dim3(256), 0, stream, cw_x, cw_z, KKx, KKz);
    hipLaunchKernelGGL(k_p1, dim3(512), dim3(512), 0, stream, x, Wd, bd, hg);
    hipLaunchKernelGGL(k_p2, dim3(512), dim3(512), 0, stream, hg, KKx, KKz,
                       g1, h1, g2, h2, W1, b1, W2, b2, ctg);
    hipLaunchKernelGGL(k_p3, dim3(512), dim3(512), 0, stream, ctg, Wu, bu, out);
}

// Round 8
// 186.973 us; speedup vs baseline: 3.7650x; 3.7650x over previous
//
#include <hip/hip_runtime.h>
#include <math.h>

#define PI_F 3.14159265358979323846f
// swizzles: XOR bank-index bits with higher address bits (bijective, both sides)
#define SWZ16(i) ((i) ^ (((i) >> 4) & 15))  // 4-bit XOR: full odd/even bank spread
#define SWZ8(i)  ((i) ^ (((i) >> 3) & 7))   // used for Wd tile in down-proj phase

// NOTE: no second __launch_bounds__ arg anywhere — empirically (1024,4)/(512,4) -> VGPR
// pinned to 64 and massive spill, (512,2) -> 128. Bodies fit <=128 naturally.

// ---------------- Kernel 0: build circular-conv tables from complex spectral weights --
__global__ __launch_bounds__(256) void build_tables(
    const float* __restrict__ cw_x, const float* __restrict__ cw_z,
    float* __restrict__ KKx, float* __restrict__ KKz)
{
    int tid = blockIdx.x * 256 + threadIdx.x;
    if (tid < 2048) {                    // X branch: S=16, V=9
        int c = tid & 7;
        int ab = tid >> 3;               // a*16+b
        int a = ab >> 4, b = ab & 15;
        float acc = 0.f;
        for (int u = 0; u < 16; ++u) {
            for (int v = 0; v < 9; ++v) {
                float m = (v == 0 || v == 8) ? 1.f : 2.f;
                int ph = (u * a + v * b) & 15;
                float th = (2.f * PI_F / 16.f) * (float)ph;
                float sn, cs;
                sincosf(th, &sn, &cs);
                const float* wp = cw_x + (size_t)((u * 9 + v) * 8 + c) * 2;
                acc += m * (wp[0] * cs - wp[1] * sn);
            }
        }
        KKx[ab * 8 + c] = acc * (1.f / 256.f);
    } else if (tid < 2048 + 512) {       // Z branch: S=8, V=5
        int e = tid - 2048;
        int c = e & 7;
        int ab = e >> 3;                 // a*8+b
        int a = ab >> 3, b = ab & 7;
        float acc = 0.f;
        for (int u = 0; u < 8; ++u) {
            for (int v = 0; v < 5; ++v) {
                float m = (v == 0 || v == 4) ? 1.f : 2.f;
                int ph = (u * a + v * b) & 7;
                float th = (2.f * PI_F / 8.f) * (float)ph;
                float sn, cs;
                sincosf(th, &sn, &cs);
                const float* wp = cw_z + (size_t)((u * 5 + v) * 8 + c) * 2;
                acc += m * (wp[0] * cs - wp[1] * sn);
            }
        }
        KKz[ab * 8 + c] = acc * (1.f / 64.f);
    }
}

// ---------------- Kernel 1: h = x @ Wd + bd (512 blocks x 512 thr, 1 job/block) -----
__global__ __launch_bounds__(512) void k_p1(
    const float* __restrict__ x, const float* __restrict__ Wd,
    const float* __restrict__ bd, float* __restrict__ hg)
{
    __shared__ float4 wds[1536];         // 24KB, swizzled
    int t = threadIdx.x;
    const float4* Wd4 = (const float4*)Wd;
    for (int i = t; i < 1536; i += 512) wds[SWZ8(i)] = Wd4[i];
    __syncthreads();

    int G = blockIdx.x * 32 + (t >> 4);  // group id, 16384 total; 5 rows/group
    int l = t & 15;
    const float4* xr = (const float4*)x + (size_t)G * 5 * 192;
    float acc[5][8];
    #pragma unroll
    for (int r = 0; r < 5; ++r)
        #pragma unroll
        for (int c = 0; c < 8; ++c) acc[r][c] = 0.f;
    #pragma unroll
    for (int j = 0; j < 12; ++j) {
        float4 v[5];
        #pragma unroll
        for (int r = 0; r < 5; ++r) v[r] = xr[(size_t)r * 192 + l + 16 * j];
        #pragma unroll
        for (int e = 0; e < 4; ++e) {
            int f4i = ((l + 16 * j) * 4 + e) * 2;        // even
            int sw = SWZ8(f4i);
            float4 w0 = wds[sw];
            float4 w1 = wds[sw ^ 1];                     // SWZ8(f4i+1)==SWZ8(f4i)^1
            #pragma unroll
            for (int r = 0; r < 5; ++r) {
                float xv = (e == 0) ? v[r].x : (e == 1) ? v[r].y : (e == 2) ? v[r].z : v[r].w;
                acc[r][0] += xv * w0.x;  acc[r][1] += xv * w0.y;
                acc[r][2] += xv * w0.z;  acc[r][3] += xv * w0.w;
                acc[r][4] += xv * w1.x;  acc[r][5] += xv * w1.y;
                acc[r][6] += xv * w1.z;  acc[r][7] += xv * w1.w;
            }
        }
    }
    #pragma unroll
    for (int off = 1; off < 16; off <<= 1)
        #pragma unroll
        for (int r = 0; r < 5; ++r)
            #pragma unroll
            for (int c = 0; c < 8; ++c)
                acc[r][c] += __shfl_xor(acc[r][c], off, 64);
    if (l < 5) {
        float o[8];
        #pragma unroll
        for (int c = 0; c < 8; ++c)
            o[c] = (l == 0) ? acc[0][c] : (l == 1) ? acc[1][c] :
                   (l == 2) ? acc[2][c] : (l == 3) ? acc[3][c] : acc[4][c];
        float4* hp = (float4*)hg + ((size_t)G * 5 + l) * 2;
        hp[0] = make_float4(o[0] + bd[0], o[1] + bd[1], o[2] + bd[2], o[3] + bd[3]);
        hp[1] = make_float4(o[4] + bd[4], o[5] + bd[5], o[6] + bd[6], o[7] + bd[7]);
    }
}

// ---------------- Kernel 2: branch conv (512 blocks x 512 thr, 1 half-batch/block) ---
__global__ __launch_bounds__(512) void k_p2(
    const float* __restrict__ hg,
    const float* __restrict__ KKx, const float* __restrict__ KKz,
    const float* __restrict__ g1v, const float* __restrict__ b1v,
    const float* __restrict__ g2v, const float* __restrict__ b2v,
    const float* __restrict__ W1, const float* __restrict__ b1m,
    const float* __restrict__ W2, const float* __restrict__ b2m,
    float* __restrict__ catg)
{
    __shared__ float4 kkx[512];       // 8KB
    __shared__ float4 kkz[128];       // 2KB
    __shared__ float4 t1x[512];       // 8KB (swizzled)
    __shared__ float4 t1z[128];       // 2KB (swizzled)

    int t = threadIdx.x;
    int batch = blockIdx.x >> 1, half = blockIdx.x & 1;

    kkx[t] = ((const float4*)KKx)[t];
    if (t < 128) kkz[t] = ((const float4*)KKz)[t];

    if (t < 320) {                       // rebuild full t1 tile (tok = t)
        const float4* hp = (const float4*)hg + ((size_t)batch * 320 + t) * 2;
        float4 r0 = hp[0], r1 = hp[1];
        float raw[8] = {r0.x, r0.y, r0.z, r0.w, r1.x, r1.y, r1.z, r1.w};
        float mean = 0.f;
        #pragma unroll
        for (int c = 0; c < 8; ++c) mean += raw[c];
        mean *= 0.125f;
        float var = 0.f;
        #pragma unroll
        for (int c = 0; c < 8; ++c) { float d = raw[c] - mean; var += d * d; }
        var *= 0.125f;
        float inv = rsqrtf(var + 1e-5f);
        float t1[8];
        #pragma unroll
        for (int c = 0; c < 8; ++c) t1[c] = (raw[c] - mean) * inv * g1v[c] + b1v[c];
        if (t >= 64) {                   // X token t-64
            int i0 = 2 * (t - 64);
            t1x[SWZ16(i0)]     = make_float4(t1[0], t1[1], t1[2], t1[3]);
            t1x[SWZ16(i0 + 1)] = make_float4(t1[4], t1[5], t1[6], t1[7]);
        } else {                         // Z token t
            int i0 = 2 * t;
            t1z[SWZ16(i0)]     = make_float4(t1[0], t1[1], t1[2], t1[3]);
            t1z[SWZ16(i0 + 1)] = make_float4(t1[4], t1[5], t1[6], t1[7]);
        }
    }
    __syncthreads();

    if (t < 160) {
        bool isX = (t < 128);
        int tok;
        float s0=0.f,s1=0.f,s2=0.f,s3=0.f,s4=0.f,s5=0.f,s6=0.f,s7=0.f;
        if (isX) {
            int xo = half * 128 + t;     // X output token 0..255
            tok = 64 + xo;
            int p = xo >> 4, q = xo & 15;
            for (int da = 0; da < 16; ++da) {
                int qp = (q - da) & 15;
                #pragma unroll
                for (int db = 0; db < 16; ++db) {
                    int pp = (p - db) & 15;
                    int si = (pp * 16 + qp) * 2;            // even
                    int sw = SWZ16(si);
                    float4 v0 = t1x[sw];
                    float4 v1 = t1x[sw ^ 1];                // SWZ16(si+1)==SWZ16(si)^1
                    int kb = (da * 16 + db) * 2;
                    float4 k0 = kkx[kb], k1 = kkx[kb + 1];  // uniform -> broadcast
                    s0 += k0.x * v0.x;  s1 += k0.y * v0.y;
                    s2 += k0.z * v0.z;  s3 += k0.w * v0.w;
                    s4 += k1.x * v1.x;  s5 += k1.y * v1.y;
                    s6 += k1.z * v1.z;  s7 += k1.w * v1.w;
                }
            }
        } else {
            int zo = half * 32 + (t - 128);  // Z output token 0..63
            tok = zo;
            int p = zo >> 3, q = zo & 7;
            for (int da = 0; da < 8; ++da) {
                int qp = (q - da) & 7;
                #pragma unroll
                for (int db = 0; db < 8; ++db) {
                    int pp = (p - db) & 7;
                    int si = (pp * 8 + qp) * 2;             // even
                    int sw = SWZ16(si);
                    float4 v0 = t1z[sw];
                    float4 v1 = t1z[sw ^ 1];
                    int kb = (da * 8 + db) * 2;
                    float4 k0 = kkz[kb], k1 = kkz[kb + 1];
                    s0 += k0.x * v0.x;  s1 += k0.y * v0.y;
                    s2 += k0.z * v0.z;  s3 += k0.w * v0.w;
                    s4 += k1.x * v1.x;  s5 += k1.y * v1.y;
                    s6 += k1.z * v1.z;  s7 += k1.w * v1.w;
                }
            }
        }

        const float4* hp = (const float4*)hg + ((size_t)batch * 320 + tok) * 2;
        float4 r0 = hp[0], r1 = hp[1];
        float raw[8] = {r0.x, r0.y, r0.z, r0.w, r1.x, r1.y, r1.z, r1.w};

        float sarr[8] = {s0, s1, s2, s3, s4, s5, s6, s7};
        float m2 = 0.f;
        #pragma unroll
        for (int c = 0; c < 8; ++c) m2 += sarr[c];
        m2 *= 0.125f;
        float v2 = 0.f;
        #pragma unroll
        for (int c = 0; c < 8; ++c) { float d = sarr[c] - m2; v2 += d * d; }
        v2 *= 0.125f;
        float inv2 = rsqrtf(v2 + 1e-5f);
        float t2[8];
        #pragma unroll
        for (int c = 0; c < 8; ++c) t2[c] = (sarr[c] - m2) * inv2 * g2v[c] + b2v[c];

        float hm[16];
        #pragma unroll
        for (int j = 0; j < 16; ++j) {
            float acc = b1m[j];
            #pragma unroll
            for (int c = 0; c < 8; ++c) acc += t2[c] * W1[c * 16 + j];
            hm[j] = 0.5f * acc * (1.f + erff(acc * 0.70710678118654752f));  // exact GELU
        }
        float o[8];
        #pragma unroll
        for (int c = 0; c < 8; ++c) {
            float acc = b2m[c];
            #pragma unroll
            for (int j = 0; j < 16; ++j) acc += hm[j] * W2[j * 8 + c];
            o[c] = acc + raw[c];
        }
        float4* cp = (float4*)catg + ((size_t)batch * 320 + tok) * 2;
        cp[0] = make_float4(o[0], o[1], o[2], o[3]);
        cp[1] = make_float4(o[4], o[5], o[6], o[7]);
    }
}

// ---------------- Kernel 3: out = cat @ Wu + bu (2560 blocks x 192 thr, 32 rows) -----
// Low register pressure by design: wr[8] f4 = 32 VGPR; ~10 blocks/CU of natural MLP.
__global__ __launch_bounds__(192) void k_p3(
    const float* __restrict__ catg, const float* __restrict__ Wu,
    const float* __restrict__ bu, float* __restrict__ out)
{
    __shared__ float crow[256];          // 32 rows x 8 ch
    int t = threadIdx.x;
    int row0 = blockIdx.x * 32;
    for (int i = t; i < 256; i += 192) crow[i] = catg[(size_t)row0 * 8 + i];
    __syncthreads();

    const float4* Wu4 = (const float4*)Wu;
    float4 wr[8];
    #pragma unroll
    for (int c = 0; c < 8; ++c) wr[c] = Wu4[c * 192 + t];
    float4 bv = ((const float4*)bu)[t];

    float4* outp = (float4*)out + (size_t)row0 * 192 + t;
    #pragma unroll 8
    for (int r = 0; r < 32; ++r) {
        const float* cr = &crow[r * 8];
        float4 a = bv;
        #pragma unroll
        for (int c = 0; c < 8; ++c) {
            float cv = cr[c];
            a.x += cv * wr[c].x;  a.y += cv * wr[c].y;
            a.z += cv * wr[c].z;  a.w += cv * wr[c].w;
        }
        outp[(size_t)r * 192] = a;       // 192 lanes x 16B = 3KB contiguous
    }
}

extern "C" void kernel_launch(void* const* d_in, const int* in_sizes, int n_in,
                              void* d_out, int out_size, void* d_ws, size_t ws_size,
                              hipStream_t stream)
{
    (void)in_sizes; (void)n_in; (void)out_size; (void)ws_size;
    const float* x    = (const float*)d_in[0];
    const float* Wd   = (const float*)d_in[1];
    const float* bd   = (const float*)d_in[2];
    const float* cw_x = (const float*)d_in[3];
    const float* cw_z = (const float*)d_in[4];
    const float* g1   = (const float*)d_in[5];
    const float* h1   = (const float*)d_in[6];
    const float* g2   = (const float*)d_in[7];
    const float* h2   = (const float*)d_in[8];
    const float* W1   = (const float*)d_in[9];
    const float* b1   = (const float*)d_in[10];
    const float* W2   = (const float*)d_in[11];
    const float* b2   = (const float*)d_in[12];
    const float* Wu   = (const float*)d_in[13];
    const float* bu   = (const float*)d_in[14];
    float* out = (float*)d_out;

    float* KKx = (float*)d_ws;          // 2048 floats
    float* KKz = KKx + 2048;            // 512 floats
    float* hg  = KKz + 512;             // 655360 floats
    float* ctg = hg + 655360;           // 655360 floats

    hipLaunchKernelGGL(build_tables, dim3(10), dim3(256), 0, stream, cw_x, cw_z, KKx, KKz);
    hipLaunchKernelGGL(k_p1, dim3(512), dim3(512), 0, stream, x, Wd, bd, hg);
    hipLaunchKernelGGL(k_p2, dim3(512), dim3(512), 0, stream, hg, KKx, KKz,
                       g1, h1, g2, h2, W1, b1, W2, b2, ctg);
    hipLaunchKernelGGL(k_p3, dim3(2560), dim3(192), 0, stream, ctg, Wu, bu, out);
}